// Round 5
// baseline (142.237 us; speedup 1.0000x reference)
//
#include <hip/hip_runtime.h>

#define ALPHA 0.2f

typedef __attribute__((ext_vector_type(8))) short short8;
typedef __attribute__((ext_vector_type(8))) unsigned short ushort8;
typedef __attribute__((ext_vector_type(4))) float f32x4;

__device__ __forceinline__ float bf2f(unsigned short u) {
    return __uint_as_float(((unsigned int)u) << 16);
}
__device__ __forceinline__ unsigned short f2bf(float f) {
    unsigned int x = __float_as_uint(f);
    unsigned int r = (x + 0x7fffu + ((x >> 16) & 1u)) >> 16;   // RNE
    return (unsigned short)r;
}

// ---------------------------------------------------------------------------
// Kernel 0: dtype detection. flags[0]=1 -> floats fp32. flags[1]=1 -> edges int64.
// ---------------------------------------------------------------------------
__global__ __launch_bounds__(256) void detect_types(const unsigned int* __restrict__ xw,
                                                    const int* __restrict__ ei32,
                                                    int* __restrict__ flags) {
    __shared__ int cnt[2];
    if (threadIdx.x == 0) { cnt[0] = 0; cnt[1] = 0; }
    __syncthreads();
    int c0 = 0, c1 = 0;
    int t = threadIdx.x;
    for (int i = 0; i < 8; i++) {
        int k = t * 8 + i;
        unsigned int u = xw[k];
        unsigned int e = (u >> 7) & 0xffu;
        if (e >= 0x58u && e <= 0x90u) c0++;
        if (ei32[2 * k + 1] != 0) c1++;
    }
    atomicAdd(&cnt[0], c0);
    atomicAdd(&cnt[1], c1);
    __syncthreads();
    if (threadIdx.x == 0) {
        flags[0] = (cnt[0] < 1200) ? 1 : 0;
        flags[1] = (cnt[1] < 1000) ? 1 : 0;
    }
}

// ---------------------------------------------------------------------------
// Kernel 1: split fp32 -> bf16 hi/lo planes. x planes [N][C]; W planes
// TRANSPOSED to [H][F][C].
// ---------------------------------------------------------------------------
__global__ __launch_bounds__(256) void split_bf16(const void* __restrict__ x_raw,
                                                  const void* __restrict__ W_raw,
                                                  unsigned short* __restrict__ x_hi,
                                                  unsigned short* __restrict__ x_lo,
                                                  unsigned short* __restrict__ wt_hi,
                                                  unsigned short* __restrict__ wt_lo,
                                                  const int* __restrict__ flags) {
    int is32 = flags[0];
    int bid = blockIdx.x, tid = threadIdx.x;
    if (bid < 1024) {                       // x: 4096*512 = 2M elems, 8/thread
        size_t base = ((size_t)bid * 256 + tid) * 8;
        ushort8 h8, l8;
        if (is32) {
            const float* xf = (const float*)x_raw;
            float4 v0 = *(const float4*)(xf + base);
            float4 v1 = *(const float4*)(xf + base + 4);
            float v[8] = {v0.x, v0.y, v0.z, v0.w, v1.x, v1.y, v1.z, v1.w};
#pragma unroll
            for (int j = 0; j < 8; j++) {
                unsigned short hi = f2bf(v[j]);
                h8[j] = hi;
                l8[j] = f2bf(v[j] - bf2f(hi));
            }
        } else {
            const ushort8* xb = (const ushort8*)x_raw;
            h8 = xb[base / 8];
            l8 = (ushort8)0;
        }
        *(ushort8*)(x_hi + base) = h8;
        *(ushort8*)(x_lo + base) = l8;
    } else {                                // W: 8*512*64 = 262144 elems
        size_t u = ((size_t)(bid - 1024) * 256 + tid) * 8;
#pragma unroll
        for (int j = 0; j < 8; j++) {
            size_t e = u + j;
            int head = (int)(e >> 15);
            int c = (int)((e >> 6) & 511);
            int f = (int)(e & 63);
            unsigned short hi, lo;
            if (is32) {
                float v = ((const float*)W_raw)[e];
                hi = f2bf(v);
                lo = f2bf(v - bf2f(hi));
            } else {
                hi = ((const unsigned short*)W_raw)[e];
                lo = 0;
            }
            size_t o = (size_t)head * 32768 + (size_t)f * 512 + c;
            wt_hi[o] = hi;
            wt_lo[o] = lo;
        }
    }
}

// ---------------------------------------------------------------------------
// Kernel 2: adjacency bitmask (dedup like the reference boolean adj).
// ---------------------------------------------------------------------------
__global__ __launch_bounds__(256) void build_adj(const int* __restrict__ ei, int E, int N,
                                                 unsigned long long* __restrict__ adj,
                                                 const int* __restrict__ flags) {
    int is64 = flags[1];
    int t = blockIdx.x * blockDim.x + threadIdx.x;
    int words = N >> 6;
    if (t < E) {
        int r = is64 ? ei[2 * t]       : ei[t];
        int c = is64 ? ei[2 * (E + t)] : ei[E + t];
        atomicOr(&adj[(size_t)r * words + (c >> 6)], 1ull << (c & 63));
    } else if (t < E + N) {
        int i = t - E;
        atomicOr(&adj[(size_t)i * words + (i >> 6)], 1ull << (i & 63));
    }
}

// ---------------------------------------------------------------------------
// Kernel 3: MFMA GEMM (bf16x3), depth-2 prefetch pipeline.
// Block: 64 rows x 64 cols (one head). 4 waves x 4 tiles of 16x16x32 MFMA.
// K' = 3 planes x 512. Outputs: h2b (bf16 [N][512]) + fp32 s_src2/s_dst2.
// ---------------------------------------------------------------------------
#define LROW 40
__global__ __launch_bounds__(256) void gemm_mfma(const unsigned short* __restrict__ xh,
                                                 const unsigned short* __restrict__ xl,
                                                 const unsigned short* __restrict__ wth,
                                                 const unsigned short* __restrict__ wtl,
                                                 const void* __restrict__ a_raw,
                                                 unsigned short* __restrict__ h2b,
                                                 float* __restrict__ s_src2,
                                                 float* __restrict__ s_dst2,
                                                 const int* __restrict__ flags) {
    __shared__ unsigned short sA[64 * LROW];
    __shared__ unsigned short sB[64 * LROW];

    int head = blockIdx.y;
    int row0 = blockIdx.x * 64;
    int tid = threadIdx.x;
    int w = tid >> 6, lane = tid & 63;
    int m = lane & 15, quad = lane >> 4;
    int sr = tid >> 2, sc = tid & 3;

    const unsigned short* Ap[3] = {xh, xl, xh};
    const unsigned short* Bp[3] = {wth, wth, wtl};
    size_t baseA = (size_t)(row0 + sr) * 512 + sc * 8;
    size_t baseB = (size_t)head * 32768 + (size_t)sr * 512 + sc * 8;

    f32x4 acc[4] = {f32x4{0.f, 0.f, 0.f, 0.f}, f32x4{0.f, 0.f, 0.f, 0.f},
                    f32x4{0.f, 0.f, 0.f, 0.f}, f32x4{0.f, 0.f, 0.f, 0.f}};

    int ldsw = sr * LROW + sc * 8;
    int ldsA = (w * 16 + m) * LROW + quad * 8;

    // depth-2 pipeline: two loads in flight
    ushort8 ra0 = *(const ushort8*)(Ap[0] + baseA);
    ushort8 rb0 = *(const ushort8*)(Bp[0] + baseB);
    ushort8 ra1 = *(const ushort8*)(Ap[0] + baseA + 32);
    ushort8 rb1 = *(const ushort8*)(Bp[0] + baseB + 32);

    for (int i = 0; i < 48; i += 2) {
        // ---- even iter: stage (ra0, rb0)
        __syncthreads();
        *(ushort8*)&sA[ldsw] = ra0;
        *(ushort8*)&sB[ldsw] = rb0;
        __syncthreads();
        {
            int inx = i + 2;
            if (inx < 48) {
                int pn = inx >> 4, kn = (inx & 15) * 32;
                ra0 = *(const ushort8*)(Ap[pn] + baseA + kn);
                rb0 = *(const ushort8*)(Bp[pn] + baseB + kn);
            }
        }
        {
            short8 af = *(const short8*)&sA[ldsA];
#pragma unroll
            for (int t = 0; t < 4; t++) {
                short8 bf = *(const short8*)&sB[(t * 16 + m) * LROW + quad * 8];
                acc[t] = __builtin_amdgcn_mfma_f32_16x16x32_bf16(af, bf, acc[t], 0, 0, 0);
            }
        }
        // ---- odd iter: stage (ra1, rb1)
        __syncthreads();
        *(ushort8*)&sA[ldsw] = ra1;
        *(ushort8*)&sB[ldsw] = rb1;
        __syncthreads();
        {
            int inx = i + 3;
            if (inx < 48) {
                int pn = inx >> 4, kn = (inx & 15) * 32;
                ra1 = *(const ushort8*)(Ap[pn] + baseA + kn);
                rb1 = *(const ushort8*)(Bp[pn] + baseB + kn);
            }
        }
        {
            short8 af = *(const short8*)&sA[ldsA];
#pragma unroll
            for (int t = 0; t < 4; t++) {
                short8 bf = *(const short8*)&sB[(t * 16 + m) * LROW + quad * 8];
                acc[t] = __builtin_amdgcn_mfma_f32_16x16x32_bf16(af, bf, acc[t], 0, 0, 0);
            }
        }
    }

    // epilogue: h2b bf16; D layout: col = lane&15, row = quad*4+reg
#pragma unroll
    for (int t = 0; t < 4; t++)
#pragma unroll
        for (int reg = 0; reg < 4; reg++) {
            int r = row0 + w * 16 + quad * 4 + reg;
            h2b[(size_t)r * 512 + head * 64 + t * 16 + m] = f2bf(acc[t][reg]);
        }

    // fused s_src/s_dst (fp32 from fp32 acc)
    float as[4], ad[4];
    if (flags[0]) {
        const float* af32 = (const float*)a_raw + head * 128;
#pragma unroll
        for (int t = 0; t < 4; t++) {
            as[t] = af32[t * 16 + m];
            ad[t] = af32[64 + t * 16 + m];
        }
    } else {
        const unsigned short* ab = (const unsigned short*)a_raw + head * 128;
#pragma unroll
        for (int t = 0; t < 4; t++) {
            as[t] = bf2f(ab[t * 16 + m]);
            ad[t] = bf2f(ab[64 + t * 16 + m]);
        }
    }
#pragma unroll
    for (int reg = 0; reg < 4; reg++) {
        float s1 = as[0] * acc[0][reg] + as[1] * acc[1][reg] + as[2] * acc[2][reg] + as[3] * acc[3][reg];
        float s2 = ad[0] * acc[0][reg] + ad[1] * acc[1][reg] + ad[2] * acc[2][reg] + ad[3] * acc[3][reg];
#pragma unroll
        for (int d = 1; d < 16; d <<= 1) {
            s1 += __shfl_xor(s1, d);
            s2 += __shfl_xor(s2, d);
        }
        if (m == 0) {
            int r = row0 + w * 16 + quad * 4 + reg;
            s_src2[(size_t)r * 8 + head] = s1;
            s_dst2[(size_t)r * 8 + head] = s2;
        }
    }
}

// ---------------------------------------------------------------------------
// Kernel 4: attention + aggregation + row softmax. Block per node i.
// Thread owns 2 output features of head hh=tid>>5; computes its own weights
// (no LDS weight staging, no barriers in the main loop).
// ---------------------------------------------------------------------------
__global__ __launch_bounds__(256) void attn_out(const unsigned short* __restrict__ h2b,
                                                const float* __restrict__ s_src2,
                                                const float* __restrict__ s_dst2,
                                                const unsigned long long* __restrict__ adj,
                                                void* __restrict__ out_raw,
                                                const int* __restrict__ flags) {
    __shared__ unsigned short nbrs[4096];
    __shared__ float sss[8];
    __shared__ float sr[8];
    __shared__ int s_cnt;

    int i = blockIdx.x;
    int tid = threadIdx.x;
    int lane = tid & 63, wid = tid >> 6;

    // Phase 1: enumerate neighbors (wave 0); stage s_src row.
    if (tid < 64) {
        unsigned long long word = adj[(size_t)i * 64 + tid];
        int cnt = __popcll(word);
        int incl = cnt;
#pragma unroll
        for (int d = 1; d < 64; d <<= 1) {
            int v = __shfl_up(incl, d);
            if (tid >= d) incl += v;
        }
        int off = incl - cnt;
        unsigned long long w = word;
        int base = tid * 64;
        while (w) {
            int b = __ffsll((unsigned long long)w) - 1;
            nbrs[off++] = (unsigned short)(base + b);
            w &= w - 1;
        }
        if (tid == 63) s_cnt = incl;
    }
    if (tid >= 64 && tid < 72) sss[tid - 64] = s_src2[(size_t)i * 8 + (tid - 64)];
    __syncthreads();
    int cnt = s_cnt;
    int hh = tid >> 5;
    float ssrc = sss[hh];

    // Pass 1: per-head max of s_dst over neighbors (redundant across head group).
    float mx = -1e30f;
    for (int t = 0; t < cnt; t++)
        mx = fmaxf(mx, s_dst2[(size_t)nbrs[t] * 8 + hh]);
    float pre = ssrc + mx;
    float maxe = pre > 0.f ? pre : ALPHA * pre;

    // Pass 2: fused weight + gather accumulate.
    float den = 0.f, ax = 0.f, ay = 0.f;
    for (int t = 0; t < cnt; t++) {
        int j = nbrs[t];
        float sd = s_dst2[(size_t)j * 8 + hh];
        float e = ssrc + sd;
        e = e > 0.f ? e : ALPHA * e;
        float w = __expf(e - maxe);
        den += w;
        unsigned int u = *(const unsigned int*)(h2b + (size_t)j * 512 + tid * 2);
        ax += w * bf2f((unsigned short)(u & 0xffffu));
        ay += w * bf2f((unsigned short)(u >> 16));
    }
    float o0 = ax / den, o1 = ay / den;

    // Phase 3: fused row softmax over 512 (2 per thread).
    float m2 = fmaxf(o0, o1);
#pragma unroll
    for (int d = 32; d; d >>= 1) m2 = fmaxf(m2, __shfl_down(m2, d));
    if (lane == 0) sr[wid] = m2;
    __syncthreads();
    float m = fmaxf(fmaxf(sr[0], sr[1]), fmaxf(sr[2], sr[3]));
    float e0 = __expf(o0 - m), e1 = __expf(o1 - m);
    float s = e0 + e1;
#pragma unroll
    for (int d = 32; d; d >>= 1) s += __shfl_down(s, d);
    __syncthreads();
    if (lane == 0) sr[wid + 4] = s;
    __syncthreads();
    s = sr[4] + sr[5] + sr[6] + sr[7];

    if (flags[0]) {
        float2* out = (float2*)out_raw;
        out[(size_t)i * 256 + tid] = make_float2(e0 / s, e1 / s);
    } else {
        unsigned int* out = (unsigned int*)out_raw;
        out[(size_t)i * 256 + tid] = (unsigned int)f2bf(e0 / s) | ((unsigned int)f2bf(e1 / s) << 16);
    }
}

// ---------------------------------------------------------------------------
extern "C" void kernel_launch(void* const* d_in, const int* in_sizes, int n_in,
                              void* d_out, int out_size, void* d_ws, size_t ws_size,
                              hipStream_t stream) {
    const int N = 4096, H = 8;
    const int E = in_sizes[1] / 2;

    const void* x = d_in[0];
    const int*  ei = (const int*)d_in[1];
    const void* W = d_in[2];
    const void* a = d_in[3];

    char* ws = (char*)d_ws;
    unsigned short* h2b = (unsigned short*)ws;                           // 4 MB
    float* s_src2 = (float*)(ws + (size_t)4 * 1024 * 1024);              // 128 KB
    float* s_dst2 = s_src2 + (size_t)N * H;                              // 128 KB
    unsigned long long* adj = (unsigned long long*)(ws + (size_t)5 * 1024 * 1024); // 2 MB
    int* flags = (int*)(ws + (size_t)7 * 1024 * 1024 + 512 * 1024);
    unsigned short* x_hi  = (unsigned short*)(ws + (size_t)8 * 1024 * 1024);       // 4 MB
    unsigned short* x_lo  = (unsigned short*)(ws + (size_t)12 * 1024 * 1024);      // 4 MB
    unsigned short* wt_hi = (unsigned short*)(ws + (size_t)16 * 1024 * 1024);      // 512 KB
    unsigned short* wt_lo = (unsigned short*)(ws + (size_t)16 * 1024 * 1024 + 512 * 1024);

    hipMemsetAsync(adj, 0, (size_t)N * (N / 8), stream);

    detect_types<<<1, 256, 0, stream>>>((const unsigned int*)x, ei, flags);
    split_bf16<<<1152, 256, 0, stream>>>(x, W, x_hi, x_lo, wt_hi, wt_lo, flags);
    build_adj<<<(E + N + 255) / 256, 256, 0, stream>>>(ei, E, N, adj, flags);
    gemm_mfma<<<dim3(N / 64, H), 256, 0, stream>>>(x_hi, x_lo, wt_hi, wt_lo, a,
                                                   h2b, s_src2, s_dst2, flags);
    attn_out<<<N, 256, 0, stream>>>(h2b, s_src2, s_dst2, adj, d_out, flags);
}